// Round 9
// baseline (641.211 us; speedup 1.0000x reference)
//
#include <hip/hip_runtime.h>
#include <cstddef>

#define BB   256    // batch = GEMM1 M
#define UU   8      // in_units
#define ISZ  1152   // in_size
#define JJ   10     // out_units
#define DD   16     // out_size
#define JD   (JJ*DD)      // 160
#define K1   (UU*ISZ)     // 9216 ; sgemm k-order: k = i*8+u
#define ICH  16           // i per sgemm block
#define NIC  (ISZ/ICH)    // 72  (split-K part count)
#define NJH  5            // j-pairs

typedef short v8s __attribute__((ext_vector_type(8)));   // 8 bf16 in 4 VGPRs
typedef float f4v __attribute__((ext_vector_type(4)));   // mfma accumulator
typedef unsigned short ush;

__device__ __forceinline__ ush f2bf(float f) {
    unsigned int u = __float_as_uint(f);
    unsigned int r = (u + 0x7fffu + ((u >> 16) & 1u)) >> 16;   // RNE
    return (ush)r;
}
__device__ __forceinline__ float bf2f(ush h) {
    return __uint_as_float(((unsigned int)h) << 16);
}

// ============ R9 DIAGNOSTIC BUILD: per-phase internal repeats ============
// One instance of each phase runs rep>1 (exact-idempotent) so its dispatch
// duration exceeds the 44us poison-fill rows and surfaces in top-5 counters.
// phase_time = dispatch_dur / rep (L2-warm-biased for reps>=2).

// ---------------- prep: x[b,u,i] -> xs[i][b*8+u] (split) + xt[u*1152+i][b] (split); b_ij=1 ----
__global__ void prep_kernel(const float* __restrict__ x,
                            ush* __restrict__ xsh, ush* __restrict__ xsl,
                            ush* __restrict__ xth, ush* __restrict__ xtl,
                            float* __restrict__ b_ij, unsigned* __restrict__ done,
                            int rep) {
    __shared__ float buf[32][8][65];
    int it = blockIdx.x;            // 18 tiles of 64 i
    int bt = blockIdx.y;            // 8 tiles of 32 b
    int i0 = it * 64, b0 = bt * 32;
    int t = threadIdx.x, lane = t & 63, wv = t >> 6;

    int flat = bt * 18 + it;
    if (flat < 45) b_ij[flat * 256 + t] = 1.0f;   // 45*256 = 11520
    if (flat == 0 && t < 16) done[t] = 0;         // mgemm last-block counters

    for (int r = 0; r < rep; ++r) {
        for (int rp = 0; rp < 64; ++rp) {
            int row = rp * 4 + wv;     // 0..255 = (bl,u)
            int bl = row >> 3, u = row & 7;
            buf[bl][u][lane] = x[(size_t)(b0 + bl) * K1 + (size_t)u * ISZ + i0 + lane];
        }
        __syncthreads();
        {   // xs[i][b*8+u]
            int bl = t >> 3, u = t & 7;
            for (int il = 0; il < 64; ++il) {
                float v = buf[bl][u][il];
                ush h = f2bf(v);
                size_t o = (size_t)(i0 + il) * 2048 + (size_t)(b0 + bl) * 8 + u;
                xsh[o] = h; xsl[o] = f2bf(v - bf2f(h));
            }
        }
        {   // xt[u*1152+i][b]
            int g = t >> 5, bl = t & 31;
            for (int pass = 0; pass < 64; ++pass) {
                int cu = pass * 8 + g;
                int u = cu >> 6, il = cu & 63;
                float v = buf[bl][u][il];
                ush h = f2bf(v);
                size_t o = (size_t)(u * ISZ + i0 + il) * BB + b0 + bl;
                xth[o] = h; xtl[o] = f2bf(v - bf2f(h));
            }
        }
        __syncthreads();   // buf reused next rep
    }
}

// ---------------- sgemm: s_part[b][ic][jd] for 2 j x 16 i per block ----------------
__global__ __launch_bounds__(256, 2) void sgemm_fused(
        const ush* __restrict__ xsh, const ush* __restrict__ xsl,
        const float* __restrict__ W, const float* __restrict__ c_tab,
        float* __restrict__ s_part, int it, int rep) {
    int ic = blockIdx.x, jh = blockIdx.y;
    int j0 = jh * 2, i0 = ic * ICH;
    int t = threadIdx.x, lane = t & 63, wv = t >> 6;
    int col = lane & 15, q = lane >> 4;

    __shared__ __align__(16) ush bh_[2][16][136];   // B^T hi [jj][d][k_local]
    __shared__ __align__(16) ush bl_[2][16][136];   // B^T lo
    __shared__ float c_lds[2][ICH];

    for (int r = 0; r < rep; ++r) {
        if (t < 2 * ICH) {
            int cj = t >> 4, ci = t & 15;
            c_lds[cj][ci] = (it == 0) ? (1.0f / 1152.0f)
                                      : c_tab[(size_t)(j0 + cj) * ISZ + i0 + ci];
        }
        __syncthreads();

        // build B tiles: 512 slots = (jj, ii, d), 2 per thread
        for (int slot = t; slot < 512; slot += 256) {
            int jj = slot >> 8, rem = slot & 255, ii = rem >> 4, d = rem & 15;
            const float* wp = W + (size_t)(i0 + ii) * 1280 + (j0 + jj) * 128 + d * 8;
            float4 wa = *(const float4*)wp;
            float4 wb = *(const float4*)(wp + 4);
            float ci = c_lds[jj][ii];
            float vals[8] = { wa.x * ci, wa.y * ci, wa.z * ci, wa.w * ci,
                              wb.x * ci, wb.y * ci, wb.z * ci, wb.w * ci };
            v8s hv, lv;
#pragma unroll
            for (int u = 0; u < 8; ++u) {
                ush h = f2bf(vals[u]);
                hv[u] = (short)h;
                lv[u] = (short)f2bf(vals[u] - bf2f(h));
            }
            *(v8s*)&bh_[jj][d][ii * 8] = hv;
            *(v8s*)&bl_[jj][d][ii * 8] = lv;
        }
        __syncthreads();

        int m_base = wv * 64;
        f4v acc[4][2];
#pragma unroll
        for (int mm = 0; mm < 4; ++mm)
#pragma unroll
            for (int jj = 0; jj < 2; ++jj) acc[mm][jj] = (f4v){0.f, 0.f, 0.f, 0.f};

#pragma unroll
        for (int s = 0; s < 4; ++s) {           // 4 k-steps x 32 k = 128 k (16 i)
            v8s bh0 = *(const v8s*)&bh_[0][col][s * 32 + q * 8];
            v8s bl0 = *(const v8s*)&bl_[0][col][s * 32 + q * 8];
            v8s bh1 = *(const v8s*)&bh_[1][col][s * 32 + q * 8];
            v8s bl1 = *(const v8s*)&bl_[1][col][s * 32 + q * 8];
            size_t abase = (size_t)(i0 + s * 4 + q) * 2048;
#pragma unroll
            for (int mm = 0; mm < 4; ++mm) {
                size_t ao = abase + (size_t)(m_base + mm * 16 + col) * 8;
                v8s ah = *(const v8s*)(xsh + ao);
                v8s al = *(const v8s*)(xsl + ao);
                acc[mm][0] = __builtin_amdgcn_mfma_f32_16x16x32_bf16(ah, bh0, acc[mm][0], 0, 0, 0);
                acc[mm][0] = __builtin_amdgcn_mfma_f32_16x16x32_bf16(ah, bl0, acc[mm][0], 0, 0, 0);
                acc[mm][0] = __builtin_amdgcn_mfma_f32_16x16x32_bf16(al, bh0, acc[mm][0], 0, 0, 0);
                acc[mm][1] = __builtin_amdgcn_mfma_f32_16x16x32_bf16(ah, bh1, acc[mm][1], 0, 0, 0);
                acc[mm][1] = __builtin_amdgcn_mfma_f32_16x16x32_bf16(ah, bl1, acc[mm][1], 0, 0, 0);
                acc[mm][1] = __builtin_amdgcn_mfma_f32_16x16x32_bf16(al, bh1, acc[mm][1], 0, 0, 0);
            }
        }
        // C/D: col = n, row = q*4+r (= b within m-tile)  [R7-verified]
#pragma unroll
        for (int mm = 0; mm < 4; ++mm)
#pragma unroll
            for (int jj = 0; jj < 2; ++jj)
#pragma unroll
                for (int r2 = 0; r2 < 4; ++r2)
                    s_part[((size_t)(m_base + mm * 16 + q * 4 + r2) * NIC + ic) * JD
                           + (j0 + jj) * DD + col] = acc[mm][jj][r2];
        __syncthreads();   // smem reused next rep
    }
}

// ---------------- reduce split-K + squash; v_out, vT bf16-split ----------------
__global__ void reduce_squash(const float* __restrict__ s_part, float* __restrict__ v,
                              ush* __restrict__ vth, ush* __restrict__ vtl, int rep) {
    int b = blockIdx.x, t = threadIdx.x;   // 192, t<160 active
    __shared__ float sm[JD];
    for (int r = 0; r < rep; ++r) {
        if (t < JD) {
            const float* sp = s_part + (size_t)b * NIC * JD + t;   // contiguous 46KB
            float s = 0.f;
#pragma unroll 8
            for (int p = 0; p < NIC; ++p) s += sp[(size_t)p * JD];
            sm[t] = s;
        }
        __syncthreads();
        if (t < JD) {
            int d = t & 15;
            float msq = 0.f;
#pragma unroll
            for (int j = 0; j < JJ; ++j) { float xx = sm[j * DD + d]; msq += xx * xx; }
            float val = msq / (1.f + msq) * sm[t] * rsqrtf(msq);
            v[(size_t)b * JD + t] = val;
            ush h = f2bf(val);
            vth[(size_t)t * BB + b] = h;
            vtl[(size_t)t * BB + b] = f2bf(val - bf2f(h));
        }
        __syncthreads();   // sm reused next rep
    }
}

// ---------------- mgemm + agreement epilogue [R7-verified] ----------------
// R6 remap: wave w -> mt = w/288, jobs (mt, 2*(w%288)+{0,1}).
// Diagnostic rep: GEMM+epilogue recomputed rep times; atomicAdd committed only
// on the last rep (exact-idempotent); p kept live via asm (rule #17, no DCE).
__global__ __launch_bounds__(256) void mgemm_agree(
        const ush* __restrict__ Ah, const ush* __restrict__ Al,
        const ush* __restrict__ Bh, const ush* __restrict__ Bl,
        const float* __restrict__ W, float* __restrict__ b_ij,
        float* __restrict__ c_tab, unsigned* __restrict__ done, int it, int rep) {
    int wv = threadIdx.x >> 6, lane = threadIdx.x & 63;
    int col = lane & 15, q = lane >> 4;
    int w = blockIdx.x * 4 + wv;        // 720 blocks -> waves 0..2879
    int mt = w / 288, nt2 = w % 288;
    int m0 = mt * 16;
    for (int r = 0; r < rep; ++r) {
#pragma unroll
        for (int jb = 0; jb < 2; ++jb) {
            int nt = nt2 * 2 + jb;
            int n0 = nt * 16;
            size_t aoff = (size_t)(m0 + col) * BB + q * 8;   // same both jobs -> L1 hit
            size_t boff = (size_t)(n0 + col) * BB + q * 8;
            f4v acc = {0.f, 0.f, 0.f, 0.f};
#pragma unroll
            for (int s = 0; s < BB / 32; ++s) {
                v8s ah = *(const v8s*)(Ah + aoff);
                v8s al = *(const v8s*)(Al + aoff);
                v8s bh = *(const v8s*)(Bh + boff);
                v8s bl = *(const v8s*)(Bl + boff);
                acc = __builtin_amdgcn_mfma_f32_16x16x32_bf16(ah, bh, acc, 0, 0, 0);
                acc = __builtin_amdgcn_mfma_f32_16x16x32_bf16(ah, bl, acc, 0, 0, 0);
                acc = __builtin_amdgcn_mfma_f32_16x16x32_bf16(al, bh, acc, 0, 0, 0);
                aoff += 32; boff += 32;
            }
            int u = nt / 72;
            int i = (nt % 72) * 16 + col;
            const float* Wp = W + (size_t)i * 1280 + mt * 128 + q * 32 + u;
            float p = Wp[0] * acc[0] + Wp[8] * acc[1] + Wp[16] * acc[2] + Wp[24] * acc[3];
            p += __shfl_xor(p, 16, 64);
            p += __shfl_xor(p, 32, 64);
            if (r == rep - 1) {
                if (q == 0) atomicAdd(&b_ij[(size_t)mt * ISZ + i], p * (1.0f / 256.0f));
            } else {
                asm volatile("" :: "v"(p));   // keep live, no commit (rule #17)
            }
        }
    }

    // ---- last-block softmax precompute (runs once): c_tab = softmax_i(b_ij) ----
    __shared__ unsigned lastf;
    asm volatile("s_waitcnt vmcnt(0)" ::: "memory");   // our atomics complete at LLC
    __syncthreads();
    if (threadIdx.x == 0) {
        unsigned old = __hip_atomic_fetch_add(&done[it], 1u,
                           __ATOMIC_RELAXED, __HIP_MEMORY_SCOPE_AGENT);
        lastf = (old == 719u);
    }
    __syncthreads();
    if (lastf) {
        for (int j = wv; j < JJ; j += 4) {            // wave wv: j = wv, wv+4, wv+8
            const float* bp = b_ij + (size_t)j * ISZ;
            float vals[18];
#pragma unroll
            for (int k = 0; k < 18; ++k) vals[k] = bp[lane + 64 * k];
            float m = -1e30f;
#pragma unroll
            for (int k = 0; k < 18; ++k) m = fmaxf(m, vals[k]);
#pragma unroll
            for (int off = 32; off; off >>= 1) m = fmaxf(m, __shfl_xor(m, off, 64));
            float ssum = 0.f;
#pragma unroll
            for (int k = 0; k < 18; ++k) ssum += __expf(vals[k] - m);
#pragma unroll
            for (int off = 32; off; off >>= 1) ssum += __shfl_xor(ssum, off, 64);
            float inv = 1.f / ssum;
#pragma unroll
            for (int k = 0; k < 18; ++k)
                c_tab[(size_t)j * ISZ + lane + 64 * k] = __expf(vals[k] - m) * inv;
        }
    }
}

extern "C" void kernel_launch(void* const* d_in, const int* in_sizes, int n_in,
                              void* d_out, int out_size, void* d_ws, size_t ws_size,
                              hipStream_t stream) {
    const float* x = (const float*)d_in[0];   // (256, 8, 1152)
    const float* W = (const float*)d_in[1];   // (1, 1152, 10, 16, 8)
    float* v_out = (float*)d_out;             // (256, 10, 16, 1)

    float* b_ij  = (float*)d_ws;                           // 11,520 f
    float* c_tab = b_ij + ISZ * JJ;                        // 11,520 f
    float* dptr  = c_tab + ISZ * JJ;
    unsigned* done = (unsigned*)dptr;                      // 64 u32 (16 used)
    float* s_part = dptr + 64;                             // 256*72*160 f (transposed)
    ush* xsh = (ush*)(s_part + (size_t)BB * NIC * JD);     // [1152][2048]
    ush* xsl = xsh + (size_t)ISZ * 2048;
    ush* xth = xsl + (size_t)ISZ * 2048;                   // [9216][256]
    ush* xtl = xth + (size_t)K1 * BB;
    ush* vth = xtl + (size_t)K1 * BB;                      // [160][256]
    ush* vtl = vth + (size_t)JD * BB;

    // Diagnostic reps: one instance of each phase amplified above the 44us
    // fill threshold so it surfaces in top-5 per-dispatch counters.
    hipLaunchKernelGGL(prep_kernel, dim3(18, 8), dim3(256), 0, stream,
                       x, xsh, xsl, xth, xtl, b_ij, done, 24);
    for (int it = 0; it < 3; ++it) {
        hipLaunchKernelGGL(sgemm_fused, dim3(NIC, NJH), dim3(256), 0, stream,
                           xsh, xsl, W, c_tab, s_part, it, it == 0 ? 8 : 1);
        hipLaunchKernelGGL(reduce_squash, dim3(BB), dim3(192), 0, stream,
                           s_part, v_out, vth, vtl, it == 0 ? 24 : 1);
        if (it < 2) {
            hipLaunchKernelGGL(mgemm_agree, dim3(720), dim3(256), 0, stream,
                               vth, vtl, xth, xtl, W, b_ij, c_tab, done, it,
                               it == 0 ? 12 : 1);
        }
    }
}

// Round 10
// 230.063 us; speedup vs baseline: 2.7871x; 2.7871x over previous
//
#include <hip/hip_runtime.h>
#include <cstddef>

#define BB   256    // batch = GEMM1 M
#define UU   8      // in_units
#define ISZ  1152   // in_size
#define JJ   10     // out_units
#define DD   16     // out_size
#define JD   (JJ*DD)      // 160
#define K1   (UU*ISZ)     // 9216 ; sgemm k-order: k = i*8+u
#define ICH  16           // i per sgemm block
#define NIC  (ISZ/ICH)    // 72  (split-K part count)
#define NJH  5            // j-pairs

typedef short v8s __attribute__((ext_vector_type(8)));   // 8 bf16 in 4 VGPRs
typedef float f4v __attribute__((ext_vector_type(4)));   // mfma accumulator
typedef unsigned short ush;

__device__ __forceinline__ ush f2bf(float f) {
    unsigned int u = __float_as_uint(f);
    unsigned int r = (u + 0x7fffu + ((u >> 16) & 1u)) >> 16;   // RNE
    return (ush)r;
}
__device__ __forceinline__ float bf2f(ush h) {
    return __uint_as_float(((unsigned int)h) << 16);
}

// ---------------- prep v2 (R10): conflict-free gathers + 16B vector stores ----
// R9 measured prep at 13.1us warm with 516K LDS conflicts/rep and 4 scalar
// 2-byte stores per element. Fix: buf[32][9][65] (bl stride 585 = 9 mod 32,
// bijective over 32 banks -> every gather <=2-way = free) and v8s stores
// (xs: 8 u contiguous per (i,b); xt: 8 b contiguous per (u,i)) -> stores / 8.
__global__ void prep_kernel(const float* __restrict__ x,
                            ush* __restrict__ xsh, ush* __restrict__ xsl,
                            ush* __restrict__ xth, ush* __restrict__ xtl,
                            float* __restrict__ b_ij, unsigned* __restrict__ done) {
    __shared__ float buf[32][9][65];   // [bl][u(8 used)][il] ; 74.9 KB
    int it = blockIdx.x;            // 18 tiles of 64 i
    int bt = blockIdx.y;            // 8 tiles of 32 b
    int i0 = it * 64, b0 = bt * 32;
    int t = threadIdx.x, lane = t & 63, wv = t >> 6;

    int flat = bt * 18 + it;
    if (flat < 45) b_ij[flat * 256 + t] = 1.0f;   // 45*256 = 11520
    if (flat == 0 && t < 16) done[t] = 0;         // mgemm last-block counters

    // load: wave row=(bl,u), lanes = il contiguous (coalesced 256B, LDS stride-1)
    for (int rep = 0; rep < 64; ++rep) {
        int row = rep * 4 + wv;     // 0..255 = (bl,u)
        int bl = row >> 3, u = row & 7;
        buf[bl][u][lane] = x[(size_t)(b0 + bl) * K1 + (size_t)u * ISZ + i0 + lane];
    }
    __syncthreads();
    {   // xs[i][b*8+u]: thread (bl, sl) gathers 8 u for (il, bl) -> v8s store
        int bl = t & 31, sl = t >> 5;          // sl 0..7
        for (int k = 0; k < 8; ++k) {
            int il = sl * 8 + k;
            v8s hv, lv;
#pragma unroll
            for (int u = 0; u < 8; ++u) {      // banks 9*bl+u+il: 2-way max (free)
                float v = buf[bl][u][il];
                ush h = f2bf(v);
                hv[u] = (short)h; lv[u] = (short)f2bf(v - bf2f(h));
            }
            size_t o = (size_t)(i0 + il) * 2048 + (size_t)(b0 + bl) * 8;
            *(v8s*)(xsh + o) = hv;             // 32 lanes x 16B = 512B contiguous
            *(v8s*)(xsl + o) = lv;
        }
    }
    {   // xt[u*1152+i][b]: thread (bq, ilq, wv) gathers 8 bl for (u, il) -> v8s
        int bq = t & 3, ilq = (t >> 2) & 15;
        int il = wv * 16 + ilq;
        for (int u = 0; u < 8; ++u) {
            v8s hv, lv;
#pragma unroll
            for (int r = 0; r < 8; ++r) {      // banks 8bq+9r+u+il: 2-way max (free)
                float v = buf[bq * 8 + r][u][il];
                ush h = f2bf(v);
                hv[r] = (short)h; lv[r] = (short)f2bf(v - bf2f(h));
            }
            size_t o = (size_t)(u * ISZ + i0 + il) * BB + b0 + bq * 8;
            *(v8s*)(xth + o) = hv;             // 64B segments, 4 lanes each
            *(v8s*)(xtl + o) = lv;
        }
    }
}

// ---------------- sgemm: s_part[b][ic][jd] for 2 j x 16 i per block ----------------
// R10 DIAG: it=0 instance runs rep=24 (idempotent) so its dispatch tops the
// counter table -> s_warm = dur/24 + sgemm's own PMC mix picks the R11 fix.
__global__ __launch_bounds__(256, 2) void sgemm_fused(
        const ush* __restrict__ xsh, const ush* __restrict__ xsl,
        const float* __restrict__ W, const float* __restrict__ c_tab,
        float* __restrict__ s_part, int it, int rep) {
    int ic = blockIdx.x, jh = blockIdx.y;
    int j0 = jh * 2, i0 = ic * ICH;
    int t = threadIdx.x, lane = t & 63, wv = t >> 6;
    int col = lane & 15, q = lane >> 4;

    __shared__ __align__(16) ush bh_[2][16][136];   // B^T hi [jj][d][k_local]
    __shared__ __align__(16) ush bl_[2][16][136];   // B^T lo
    __shared__ float c_lds[2][ICH];

    for (int r = 0; r < rep; ++r) {
        if (t < 2 * ICH) {
            int cj = t >> 4, ci = t & 15;
            c_lds[cj][ci] = (it == 0) ? (1.0f / 1152.0f)
                                      : c_tab[(size_t)(j0 + cj) * ISZ + i0 + ci];
        }
        __syncthreads();

        // build B tiles: 512 slots = (jj, ii, d), 2 per thread
        for (int slot = t; slot < 512; slot += 256) {
            int jj = slot >> 8, rem = slot & 255, ii = rem >> 4, d = rem & 15;
            const float* wp = W + (size_t)(i0 + ii) * 1280 + (j0 + jj) * 128 + d * 8;
            float4 wa = *(const float4*)wp;
            float4 wb = *(const float4*)(wp + 4);
            float ci = c_lds[jj][ii];
            float vals[8] = { wa.x * ci, wa.y * ci, wa.z * ci, wa.w * ci,
                              wb.x * ci, wb.y * ci, wb.z * ci, wb.w * ci };
            v8s hv, lv;
#pragma unroll
            for (int u = 0; u < 8; ++u) {
                ush h = f2bf(vals[u]);
                hv[u] = (short)h;
                lv[u] = (short)f2bf(vals[u] - bf2f(h));
            }
            *(v8s*)&bh_[jj][d][ii * 8] = hv;
            *(v8s*)&bl_[jj][d][ii * 8] = lv;
        }
        __syncthreads();

        int m_base = wv * 64;
        f4v acc[4][2];
#pragma unroll
        for (int mm = 0; mm < 4; ++mm)
#pragma unroll
            for (int jj = 0; jj < 2; ++jj) acc[mm][jj] = (f4v){0.f, 0.f, 0.f, 0.f};

#pragma unroll
        for (int s = 0; s < 4; ++s) {           // 4 k-steps x 32 k = 128 k (16 i)
            v8s bh0 = *(const v8s*)&bh_[0][col][s * 32 + q * 8];
            v8s bl0 = *(const v8s*)&bl_[0][col][s * 32 + q * 8];
            v8s bh1 = *(const v8s*)&bh_[1][col][s * 32 + q * 8];
            v8s bl1 = *(const v8s*)&bl_[1][col][s * 32 + q * 8];
            size_t abase = (size_t)(i0 + s * 4 + q) * 2048;
#pragma unroll
            for (int mm = 0; mm < 4; ++mm) {
                size_t ao = abase + (size_t)(m_base + mm * 16 + col) * 8;
                v8s ah = *(const v8s*)(xsh + ao);
                v8s al = *(const v8s*)(xsl + ao);
                acc[mm][0] = __builtin_amdgcn_mfma_f32_16x16x32_bf16(ah, bh0, acc[mm][0], 0, 0, 0);
                acc[mm][0] = __builtin_amdgcn_mfma_f32_16x16x32_bf16(ah, bl0, acc[mm][0], 0, 0, 0);
                acc[mm][0] = __builtin_amdgcn_mfma_f32_16x16x32_bf16(al, bh0, acc[mm][0], 0, 0, 0);
                acc[mm][1] = __builtin_amdgcn_mfma_f32_16x16x32_bf16(ah, bh1, acc[mm][1], 0, 0, 0);
                acc[mm][1] = __builtin_amdgcn_mfma_f32_16x16x32_bf16(ah, bl1, acc[mm][1], 0, 0, 0);
                acc[mm][1] = __builtin_amdgcn_mfma_f32_16x16x32_bf16(al, bh1, acc[mm][1], 0, 0, 0);
            }
        }
        // C/D: col = n, row = q*4+r (= b within m-tile)  [R7-verified]
#pragma unroll
        for (int mm = 0; mm < 4; ++mm)
#pragma unroll
            for (int jj = 0; jj < 2; ++jj)
#pragma unroll
                for (int r2 = 0; r2 < 4; ++r2)
                    s_part[((size_t)(m_base + mm * 16 + q * 4 + r2) * NIC + ic) * JD
                           + (j0 + jj) * DD + col] = acc[mm][jj][r2];
        __syncthreads();   // smem reused next rep
    }
}

// ---------------- reduce split-K + squash; v_out, vT bf16-split ----------------
__global__ void reduce_squash(const float* __restrict__ s_part, float* __restrict__ v,
                              ush* __restrict__ vth, ush* __restrict__ vtl) {
    int b = blockIdx.x, t = threadIdx.x;   // 192, t<160 active
    __shared__ float sm[JD];
    if (t < JD) {
        const float* sp = s_part + (size_t)b * NIC * JD + t;   // contiguous 46KB region
        float s = 0.f;
#pragma unroll 8
        for (int p = 0; p < NIC; ++p) s += sp[(size_t)p * JD];
        sm[t] = s;
    }
    __syncthreads();
    if (t < JD) {
        int d = t & 15;
        float msq = 0.f;
#pragma unroll
        for (int j = 0; j < JJ; ++j) { float xx = sm[j * DD + d]; msq += xx * xx; }
        float val = msq / (1.f + msq) * sm[t] * rsqrtf(msq);
        v[(size_t)b * JD + t] = val;
        ush h = f2bf(val);
        vth[(size_t)t * BB + b] = h;
        vtl[(size_t)t * BB + b] = f2bf(val - bf2f(h));
    }
}

// ---------------- mgemm + agreement epilogue [R7-verified] ----------------
// wave w -> mt = w/288, jobs (mt, 2*(w%288)+{0,1}): same-mt A reuse (R6).
// Last finished block computes c_tab = softmax(b_ij) for next sgemm (R6).
__global__ __launch_bounds__(256) void mgemm_agree(
        const ush* __restrict__ Ah, const ush* __restrict__ Al,
        const ush* __restrict__ Bh, const ush* __restrict__ Bl,
        const float* __restrict__ W, float* __restrict__ b_ij,
        float* __restrict__ c_tab, unsigned* __restrict__ done, int it) {
    int wv = threadIdx.x >> 6, lane = threadIdx.x & 63;
    int col = lane & 15, q = lane >> 4;
    int w = blockIdx.x * 4 + wv;        // 720 blocks -> waves 0..2879
    int mt = w / 288, nt2 = w % 288;
    int m0 = mt * 16;
#pragma unroll
    for (int rep = 0; rep < 2; ++rep) {
        int nt = nt2 * 2 + rep;
        int n0 = nt * 16;
        size_t aoff = (size_t)(m0 + col) * BB + q * 8;   // same both reps -> L1 hit
        size_t boff = (size_t)(n0 + col) * BB + q * 8;
        f4v acc = {0.f, 0.f, 0.f, 0.f};
#pragma unroll
        for (int s = 0; s < BB / 32; ++s) {
            v8s ah = *(const v8s*)(Ah + aoff);
            v8s al = *(const v8s*)(Al + aoff);
            v8s bh = *(const v8s*)(Bh + boff);
            v8s bl = *(const v8s*)(Bl + boff);
            acc = __builtin_amdgcn_mfma_f32_16x16x32_bf16(ah, bh, acc, 0, 0, 0);
            acc = __builtin_amdgcn_mfma_f32_16x16x32_bf16(ah, bl, acc, 0, 0, 0);
            acc = __builtin_amdgcn_mfma_f32_16x16x32_bf16(al, bh, acc, 0, 0, 0);
            aoff += 32; boff += 32;
        }
        int u = nt / 72;
        int i = (nt % 72) * 16 + col;
        const float* Wp = W + (size_t)i * 1280 + mt * 128 + q * 32 + u;
        float p = Wp[0] * acc[0] + Wp[8] * acc[1] + Wp[16] * acc[2] + Wp[24] * acc[3];
        p += __shfl_xor(p, 16, 64);
        p += __shfl_xor(p, 32, 64);
        if (q == 0) atomicAdd(&b_ij[(size_t)mt * ISZ + i], p * (1.0f / 256.0f));
    }

    // ---- last-block softmax precompute: c_tab[j][i] = softmax_i(b_ij[j][i]) ----
    __shared__ unsigned lastf;
    asm volatile("s_waitcnt vmcnt(0)" ::: "memory");   // our atomics complete at LLC
    __syncthreads();
    if (threadIdx.x == 0) {
        unsigned old = __hip_atomic_fetch_add(&done[it], 1u,
                           __ATOMIC_RELAXED, __HIP_MEMORY_SCOPE_AGENT);
        lastf = (old == 719u);
    }
    __syncthreads();
    if (lastf) {
        for (int j = wv; j < JJ; j += 4) {            // wave wv: j = wv, wv+4, wv+8
            const float* bp = b_ij + (size_t)j * ISZ;
            float vals[18];
#pragma unroll
            for (int k = 0; k < 18; ++k) vals[k] = bp[lane + 64 * k];
            float m = -1e30f;
#pragma unroll
            for (int k = 0; k < 18; ++k) m = fmaxf(m, vals[k]);
#pragma unroll
            for (int off = 32; off; off >>= 1) m = fmaxf(m, __shfl_xor(m, off, 64));
            float ssum = 0.f;
#pragma unroll
            for (int k = 0; k < 18; ++k) ssum += __expf(vals[k] - m);
#pragma unroll
            for (int off = 32; off; off >>= 1) ssum += __shfl_xor(ssum, off, 64);
            float inv = 1.f / ssum;
#pragma unroll
            for (int k = 0; k < 18; ++k)
                c_tab[(size_t)j * ISZ + lane + 64 * k] = __expf(vals[k] - m) * inv;
        }
    }
}

extern "C" void kernel_launch(void* const* d_in, const int* in_sizes, int n_in,
                              void* d_out, int out_size, void* d_ws, size_t ws_size,
                              hipStream_t stream) {
    const float* x = (const float*)d_in[0];   // (256, 8, 1152)
    const float* W = (const float*)d_in[1];   // (1, 1152, 10, 16, 8)
    float* v_out = (float*)d_out;             // (256, 10, 16, 1)

    float* b_ij  = (float*)d_ws;                           // 11,520 f
    float* c_tab = b_ij + ISZ * JJ;                        // 11,520 f
    float* dptr  = c_tab + ISZ * JJ;
    unsigned* done = (unsigned*)dptr;                      // 64 u32 (16 used)
    float* s_part = dptr + 64;                             // 256*72*160 f (transposed)
    ush* xsh = (ush*)(s_part + (size_t)BB * NIC * JD);     // [1152][2048]
    ush* xsl = xsh + (size_t)ISZ * 2048;
    ush* xth = xsl + (size_t)ISZ * 2048;                   // [9216][256]
    ush* xtl = xth + (size_t)K1 * BB;
    ush* vth = xtl + (size_t)K1 * BB;                      // [160][256]
    ush* vtl = vth + (size_t)JD * BB;

    hipLaunchKernelGGL(prep_kernel, dim3(18, 8), dim3(256), 0, stream,
                       x, xsh, xsl, xth, xtl, b_ij, done);
    for (int it = 0; it < 3; ++it) {
        // R10 DIAG: it=0 sgemm amplified x24 to surface in top-5 counters
        hipLaunchKernelGGL(sgemm_fused, dim3(NIC, NJH), dim3(256), 0, stream,
                           xsh, xsl, W, c_tab, s_part, it, it == 0 ? 24 : 1);
        hipLaunchKernelGGL(reduce_squash, dim3(BB), dim3(192), 0, stream,
                           s_part, v_out, vth, vtl);
        if (it < 2) {
            hipLaunchKernelGGL(mgemm_agree, dim3(720), dim3(256), 0, stream,
                               vth, vtl, xth, xtl, W, b_ij, c_tab, done, it);
        }
    }
}

// Round 11
// 176.430 us; speedup vs baseline: 3.6344x; 1.3040x over previous
//
#include <hip/hip_runtime.h>
#include <cstddef>

#define BB   256    // batch = GEMM1 M
#define UU   8      // in_units
#define ISZ  1152   // in_size
#define JJ   10     // out_units
#define DD   16     // out_size
#define JD   (JJ*DD)      // 160
#define K1   (UU*ISZ)     // 9216 ; sgemm k-order: k = i*8+u
#define ICH  16           // i per sgemm block
#define NIC  (ISZ/ICH)    // 72  (split-K part count)
#define NJH  5            // j-pairs

typedef short v8s __attribute__((ext_vector_type(8)));   // 8 bf16 in 4 VGPRs
typedef float f4v __attribute__((ext_vector_type(4)));   // mfma accumulator
typedef unsigned short ush;

__device__ __forceinline__ ush f2bf(float f) {
    unsigned int u = __float_as_uint(f);
    unsigned int r = (u + 0x7fffu + ((u >> 16) & 1u)) >> 16;   // RNE
    return (ush)r;
}
__device__ __forceinline__ float bf2f(ush h) {
    return __uint_as_float(((unsigned int)h) << 16);
}

// ---------------- prep v2 (R10-measured win): conflict-free gathers + 16B stores ----
// R9: prep v1 = 13.1us warm (516K LDS conflicts/rep, 4 scalar 2B stores/elem).
// v2: buf[32][9][65] (bl word-stride 585; all gathers <=2-way = free) + v8s
// stores (xs: 8 u contiguous; xt: 8 b contiguous) -> stores/8. ~20us off total.
__global__ void prep_kernel(const float* __restrict__ x,
                            ush* __restrict__ xsh, ush* __restrict__ xsl,
                            ush* __restrict__ xth, ush* __restrict__ xtl,
                            float* __restrict__ b_ij, unsigned* __restrict__ done) {
    __shared__ float buf[32][9][65];   // [bl][u(8 used)][il] ; 74.9 KB
    int it = blockIdx.x;            // 18 tiles of 64 i
    int bt = blockIdx.y;            // 8 tiles of 32 b
    int i0 = it * 64, b0 = bt * 32;
    int t = threadIdx.x, lane = t & 63, wv = t >> 6;

    int flat = bt * 18 + it;
    if (flat < 45) b_ij[flat * 256 + t] = 1.0f;   // 45*256 = 11520
    if (flat == 0 && t < 16) done[t] = 0;         // mgemm last-block counters

    // load: wave row=(bl,u), lanes = il contiguous (coalesced 256B, LDS stride-1)
    for (int rep = 0; rep < 64; ++rep) {
        int row = rep * 4 + wv;     // 0..255 = (bl,u)
        int bl = row >> 3, u = row & 7;
        buf[bl][u][lane] = x[(size_t)(b0 + bl) * K1 + (size_t)u * ISZ + i0 + lane];
    }
    __syncthreads();
    {   // xs[i][b*8+u]: thread (bl, sl) gathers 8 u for (il, bl) -> v8s store
        int bl = t & 31, sl = t >> 5;          // sl 0..7
        for (int k = 0; k < 8; ++k) {
            int il = sl * 8 + k;
            v8s hv, lv;
#pragma unroll
            for (int u = 0; u < 8; ++u) {      // banks 9*bl+u+il: <=2-way (free)
                float v = buf[bl][u][il];
                ush h = f2bf(v);
                hv[u] = (short)h; lv[u] = (short)f2bf(v - bf2f(h));
            }
            size_t o = (size_t)(i0 + il) * 2048 + (size_t)(b0 + bl) * 8;
            *(v8s*)(xsh + o) = hv;             // 32 lanes x 16B = 512B contiguous
            *(v8s*)(xsl + o) = lv;
        }
    }
    {   // xt[u*1152+i][b]: thread (bq, ilq, wv) gathers 8 bl for (u, il) -> v8s
        int bq = t & 3, ilq = (t >> 2) & 15;
        int il = wv * 16 + ilq;
        for (int u = 0; u < 8; ++u) {
            v8s hv, lv;
#pragma unroll
            for (int r = 0; r < 8; ++r) {      // banks 8bq+9r+u+il: <=2-way (free)
                float v = buf[bq * 8 + r][u][il];
                ush h = f2bf(v);
                hv[r] = (short)h; lv[r] = (short)f2bf(v - bf2f(h));
            }
            size_t o = (size_t)(u * ISZ + i0 + il) * BB + b0 + bq * 8;
            *(v8s*)(xth + o) = hv;             // 64B segments, 4 lanes each
            *(v8s*)(xtl + o) = lv;
        }
    }
}

// ---------------- sgemm: s_part[b][ic][jd] for 2 j x 16 i per block ----------------
// R10-measured: 3.2us warm / ~7us cold; MfmaUtil 29% warm -- latency-bound,
// no internal lever. grid (72,5): blocks sharing an A-slice are 72 apart ->
// same XCD -> L2-shared (R6). c_ij precomputed in c_tab by mgemm's last block.
__global__ __launch_bounds__(256, 2) void sgemm_fused(
        const ush* __restrict__ xsh, const ush* __restrict__ xsl,
        const float* __restrict__ W, const float* __restrict__ c_tab,
        float* __restrict__ s_part, int it) {
    int ic = blockIdx.x, jh = blockIdx.y;
    int j0 = jh * 2, i0 = ic * ICH;
    int t = threadIdx.x, lane = t & 63, wv = t >> 6;
    int col = lane & 15, q = lane >> 4;

    __shared__ __align__(16) ush bh_[2][16][136];   // B^T hi [jj][d][k_local]
    __shared__ __align__(16) ush bl_[2][16][136];   // B^T lo
    __shared__ float c_lds[2][ICH];

    if (t < 2 * ICH) {
        int cj = t >> 4, ci = t & 15;
        c_lds[cj][ci] = (it == 0) ? (1.0f / 1152.0f)
                                  : c_tab[(size_t)(j0 + cj) * ISZ + i0 + ci];
    }
    __syncthreads();

    // build B tiles: 512 slots = (jj, ii, d), 2 per thread
    for (int slot = t; slot < 512; slot += 256) {
        int jj = slot >> 8, rem = slot & 255, ii = rem >> 4, d = rem & 15;
        const float* wp = W + (size_t)(i0 + ii) * 1280 + (j0 + jj) * 128 + d * 8;
        float4 wa = *(const float4*)wp;
        float4 wb = *(const float4*)(wp + 4);
        float ci = c_lds[jj][ii];
        float vals[8] = { wa.x * ci, wa.y * ci, wa.z * ci, wa.w * ci,
                          wb.x * ci, wb.y * ci, wb.z * ci, wb.w * ci };
        v8s hv, lv;
#pragma unroll
        for (int u = 0; u < 8; ++u) {
            ush h = f2bf(vals[u]);
            hv[u] = (short)h;
            lv[u] = (short)f2bf(vals[u] - bf2f(h));
        }
        *(v8s*)&bh_[jj][d][ii * 8] = hv;
        *(v8s*)&bl_[jj][d][ii * 8] = lv;
    }
    __syncthreads();

    int m_base = wv * 64;
    f4v acc[4][2];
#pragma unroll
    for (int mm = 0; mm < 4; ++mm)
#pragma unroll
        for (int jj = 0; jj < 2; ++jj) acc[mm][jj] = (f4v){0.f, 0.f, 0.f, 0.f};

#pragma unroll
    for (int s = 0; s < 4; ++s) {           // 4 k-steps x 32 k = 128 k (16 i)
        v8s bh0 = *(const v8s*)&bh_[0][col][s * 32 + q * 8];
        v8s bl0 = *(const v8s*)&bl_[0][col][s * 32 + q * 8];
        v8s bh1 = *(const v8s*)&bh_[1][col][s * 32 + q * 8];
        v8s bl1 = *(const v8s*)&bl_[1][col][s * 32 + q * 8];
        size_t abase = (size_t)(i0 + s * 4 + q) * 2048;
#pragma unroll
        for (int mm = 0; mm < 4; ++mm) {
            size_t ao = abase + (size_t)(m_base + mm * 16 + col) * 8;
            v8s ah = *(const v8s*)(xsh + ao);
            v8s al = *(const v8s*)(xsl + ao);
            acc[mm][0] = __builtin_amdgcn_mfma_f32_16x16x32_bf16(ah, bh0, acc[mm][0], 0, 0, 0);
            acc[mm][0] = __builtin_amdgcn_mfma_f32_16x16x32_bf16(ah, bl0, acc[mm][0], 0, 0, 0);
            acc[mm][0] = __builtin_amdgcn_mfma_f32_16x16x32_bf16(al, bh0, acc[mm][0], 0, 0, 0);
            acc[mm][1] = __builtin_amdgcn_mfma_f32_16x16x32_bf16(ah, bh1, acc[mm][1], 0, 0, 0);
            acc[mm][1] = __builtin_amdgcn_mfma_f32_16x16x32_bf16(ah, bl1, acc[mm][1], 0, 0, 0);
            acc[mm][1] = __builtin_amdgcn_mfma_f32_16x16x32_bf16(al, bh1, acc[mm][1], 0, 0, 0);
        }
    }
    // C/D: col = n, row = q*4+r (= b within m-tile)  [R7-verified]
    // s_part[b][ic][jd] (transposed) -> reduce reads contiguous 46KB/block
#pragma unroll
    for (int mm = 0; mm < 4; ++mm)
#pragma unroll
        for (int jj = 0; jj < 2; ++jj)
#pragma unroll
            for (int r = 0; r < 4; ++r)
                s_part[((size_t)(m_base + mm * 16 + q * 4 + r) * NIC + ic) * JD
                       + (j0 + jj) * DD + col] = acc[mm][jj][r];
}

// ---------------- reduce split-K + squash; v_out (last it) / vT bf16 (it<2) ----
__global__ void reduce_squash(const float* __restrict__ s_part, float* __restrict__ v,
                              ush* __restrict__ vth, ush* __restrict__ vtl, int it) {
    int b = blockIdx.x, t = threadIdx.x;   // 192, t<160 active
    __shared__ float sm[JD];
    if (t < JD) {
        const float* sp = s_part + (size_t)b * NIC * JD + t;   // contiguous 46KB region
        float s = 0.f;
#pragma unroll 8
        for (int p = 0; p < NIC; ++p) s += sp[(size_t)p * JD];
        sm[t] = s;
    }
    __syncthreads();
    if (t < JD) {
        int d = t & 15;
        float msq = 0.f;
#pragma unroll
        for (int j = 0; j < JJ; ++j) { float xx = sm[j * DD + d]; msq += xx * xx; }
        float val = msq / (1.f + msq) * sm[t] * rsqrtf(msq);
        if (it == 2) {
            v[(size_t)b * JD + t] = val;      // final output only
        } else {
            ush h = f2bf(val);
            vth[(size_t)t * BB + b] = h;
            vtl[(size_t)t * BB + b] = f2bf(val - bf2f(h));
        }
    }
}

// ---------------- mgemm + agreement epilogue [R7-verified] ----------------
// wave w -> mt = w/288, jobs (mt, 2*(w%288)+{0,1}): same-mt A reuse (R6).
// Last finished block computes c_tab = softmax(b_ij) for next sgemm (R6).
__global__ __launch_bounds__(256) void mgemm_agree(
        const ush* __restrict__ Ah, const ush* __restrict__ Al,
        const ush* __restrict__ Bh, const ush* __restrict__ Bl,
        const float* __restrict__ W, float* __restrict__ b_ij,
        float* __restrict__ c_tab, unsigned* __restrict__ done, int it) {
    int wv = threadIdx.x >> 6, lane = threadIdx.x & 63;
    int col = lane & 15, q = lane >> 4;
    int w = blockIdx.x * 4 + wv;        // 720 blocks -> waves 0..2879
    int mt = w / 288, nt2 = w % 288;
    int m0 = mt * 16;
#pragma unroll
    for (int rep = 0; rep < 2; ++rep) {
        int nt = nt2 * 2 + rep;
        int n0 = nt * 16;
        size_t aoff = (size_t)(m0 + col) * BB + q * 8;   // same both reps -> L1 hit
        size_t boff = (size_t)(n0 + col) * BB + q * 8;
        f4v acc = {0.f, 0.f, 0.f, 0.f};
#pragma unroll
        for (int s = 0; s < BB / 32; ++s) {
            v8s ah = *(const v8s*)(Ah + aoff);
            v8s al = *(const v8s*)(Al + aoff);
            v8s bh = *(const v8s*)(Bh + boff);
            v8s bl = *(const v8s*)(Bl + boff);
            acc = __builtin_amdgcn_mfma_f32_16x16x32_bf16(ah, bh, acc, 0, 0, 0);
            acc = __builtin_amdgcn_mfma_f32_16x16x32_bf16(ah, bl, acc, 0, 0, 0);
            acc = __builtin_amdgcn_mfma_f32_16x16x32_bf16(al, bh, acc, 0, 0, 0);
            aoff += 32; boff += 32;
        }
        int u = nt / 72;
        int i = (nt % 72) * 16 + col;
        const float* Wp = W + (size_t)i * 1280 + mt * 128 + q * 32 + u;
        float p = Wp[0] * acc[0] + Wp[8] * acc[1] + Wp[16] * acc[2] + Wp[24] * acc[3];
        p += __shfl_xor(p, 16, 64);
        p += __shfl_xor(p, 32, 64);
        if (q == 0) atomicAdd(&b_ij[(size_t)mt * ISZ + i], p * (1.0f / 256.0f));
    }

    // ---- last-block softmax precompute: c_tab[j][i] = softmax_i(b_ij[j][i]) ----
    __shared__ unsigned lastf;
    asm volatile("s_waitcnt vmcnt(0)" ::: "memory");   // our atomics complete at LLC
    __syncthreads();
    if (threadIdx.x == 0) {
        unsigned old = __hip_atomic_fetch_add(&done[it], 1u,
                           __ATOMIC_RELAXED, __HIP_MEMORY_SCOPE_AGENT);
        lastf = (old == 719u);
    }
    __syncthreads();
    if (lastf) {
        for (int j = wv; j < JJ; j += 4) {            // wave wv: j = wv, wv+4, wv+8
            const float* bp = b_ij + (size_t)j * ISZ;
            float vals[18];
#pragma unroll
            for (int k = 0; k < 18; ++k) vals[k] = bp[lane + 64 * k];
            float m = -1e30f;
#pragma unroll
            for (int k = 0; k < 18; ++k) m = fmaxf(m, vals[k]);
#pragma unroll
            for (int off = 32; off; off >>= 1) m = fmaxf(m, __shfl_xor(m, off, 64));
            float ssum = 0.f;
#pragma unroll
            for (int k = 0; k < 18; ++k) ssum += __expf(vals[k] - m);
#pragma unroll
            for (int off = 32; off; off >>= 1) ssum += __shfl_xor(ssum, off, 64);
            float inv = 1.f / ssum;
#pragma unroll
            for (int k = 0; k < 18; ++k)
                c_tab[(size_t)j * ISZ + lane + 64 * k] = __expf(vals[k] - m) * inv;
        }
    }
}

extern "C" void kernel_launch(void* const* d_in, const int* in_sizes, int n_in,
                              void* d_out, int out_size, void* d_ws, size_t ws_size,
                              hipStream_t stream) {
    const float* x = (const float*)d_in[0];   // (256, 8, 1152)
    const float* W = (const float*)d_in[1];   // (1, 1152, 10, 16, 8)
    float* v_out = (float*)d_out;             // (256, 10, 16, 1)

    float* b_ij  = (float*)d_ws;                           // 11,520 f
    float* c_tab = b_ij + ISZ * JJ;                        // 11,520 f
    float* dptr  = c_tab + ISZ * JJ;
    unsigned* done = (unsigned*)dptr;                      // 64 u32 (16 used)
    float* s_part = dptr + 64;                             // 256*72*160 f (transposed)
    ush* xsh = (ush*)(s_part + (size_t)BB * NIC * JD);     // [1152][2048]
    ush* xsl = xsh + (size_t)ISZ * 2048;
    ush* xth = xsl + (size_t)ISZ * 2048;                   // [9216][256]
    ush* xtl = xth + (size_t)K1 * BB;
    ush* vth = xtl + (size_t)K1 * BB;                      // [160][256]
    ush* vtl = vth + (size_t)JD * BB;

    hipLaunchKernelGGL(prep_kernel, dim3(18, 8), dim3(256), 0, stream,
                       x, xsh, xsl, xth, xtl, b_ij, done);
    for (int it = 0; it < 3; ++it) {
        hipLaunchKernelGGL(sgemm_fused, dim3(NIC, NJH), dim3(256), 0, stream,
                           xsh, xsl, W, c_tab, s_part, it);
        hipLaunchKernelGGL(reduce_squash, dim3(BB), dim3(192), 0, stream,
                           s_part, v_out, vth, vtl, it);
        if (it < 2) {
            hipLaunchKernelGGL(mgemm_agree, dim3(720), dim3(256), 0, stream,
                               vth, vtl, xth, xtl, W, b_ij, c_tab, done, it);
        }
    }
}

// Round 13
// 172.540 us; speedup vs baseline: 3.7163x; 1.0225x over previous
//
#include <hip/hip_runtime.h>
#include <cstddef>

#define BB   256    // batch = GEMM1 M
#define UU   8      // in_units
#define ISZ  1152   // in_size
#define JJ   10     // out_units
#define DD   16     // out_size
#define JD   (JJ*DD)      // 160
#define K1   (UU*ISZ)     // 9216 ; sgemm k-order: k = i*8+u
#define ICH  16           // i per sgemm block
#define NIC  (ISZ/ICH)    // 72  (split-K part count)
#define NJH  5            // j-pairs

typedef short v8s __attribute__((ext_vector_type(8)));   // 8 bf16 in 4 VGPRs
typedef float f4v __attribute__((ext_vector_type(4)));   // mfma accumulator
typedef unsigned short ush;

__device__ __forceinline__ ush f2bf(float f) {
    unsigned int u = __float_as_uint(f);
    unsigned int r = (u + 0x7fffu + ((u >> 16) & 1u)) >> 16;   // RNE
    return (ush)r;
}
__device__ __forceinline__ float bf2f(ush h) {
    return __uint_as_float(((unsigned int)h) << 16);
}

// ---------------- prep v2 (R10-measured win): conflict-free gathers + 16B stores ----
// R9: prep v1 = 13.1us warm (516K LDS conflicts/rep, 4 scalar 2B stores/elem).
// v2: buf[32][9][65] (bl word-stride 585; all gathers <=2-way = free) + v8s
// stores (xs: 8 u contiguous; xt: 8 b contiguous) -> stores/8.
__global__ void prep_kernel(const float* __restrict__ x,
                            ush* __restrict__ xsh, ush* __restrict__ xsl,
                            ush* __restrict__ xth, ush* __restrict__ xtl,
                            float* __restrict__ b_ij, unsigned* __restrict__ done) {
    __shared__ float buf[32][9][65];   // [bl][u(8 used)][il] ; 74.9 KB
    int it = blockIdx.x;            // 18 tiles of 64 i
    int bt = blockIdx.y;            // 8 tiles of 32 b
    int i0 = it * 64, b0 = bt * 32;
    int t = threadIdx.x, lane = t & 63, wv = t >> 6;

    int flat = bt * 18 + it;
    if (flat < 45) b_ij[flat * 256 + t] = 1.0f;   // 45*256 = 11520
    if (flat == 0 && t < 16) done[t] = 0;         // mgemm last-block counters

    // load: wave row=(bl,u), lanes = il contiguous (coalesced 256B, LDS stride-1)
    for (int rep = 0; rep < 64; ++rep) {
        int row = rep * 4 + wv;     // 0..255 = (bl,u)
        int bl = row >> 3, u = row & 7;
        buf[bl][u][lane] = x[(size_t)(b0 + bl) * K1 + (size_t)u * ISZ + i0 + lane];
    }
    __syncthreads();
    {   // xs[i][b*8+u]: thread (bl, sl) gathers 8 u for (il, bl) -> v8s store
        int bl = t & 31, sl = t >> 5;          // sl 0..7
        for (int k = 0; k < 8; ++k) {
            int il = sl * 8 + k;
            v8s hv, lv;
#pragma unroll
            for (int u = 0; u < 8; ++u) {      // banks 9*bl+u+il: <=2-way (free)
                float v = buf[bl][u][il];
                ush h = f2bf(v);
                hv[u] = (short)h; lv[u] = (short)f2bf(v - bf2f(h));
            }
            size_t o = (size_t)(i0 + il) * 2048 + (size_t)(b0 + bl) * 8;
            *(v8s*)(xsh + o) = hv;             // 32 lanes x 16B = 512B contiguous
            *(v8s*)(xsl + o) = lv;
        }
    }
    {   // xt[u*1152+i][b]: thread (bq, ilq, wv) gathers 8 bl for (u, il) -> v8s
        int bq = t & 3, ilq = (t >> 2) & 15;
        int il = wv * 16 + ilq;
        for (int u = 0; u < 8; ++u) {
            v8s hv, lv;
#pragma unroll
            for (int r = 0; r < 8; ++r) {      // banks 8bq+9r+u+il: <=2-way (free)
                float v = buf[bq * 8 + r][u][il];
                ush h = f2bf(v);
                hv[r] = (short)h; lv[r] = (short)f2bf(v - bf2f(h));
            }
            size_t o = (size_t)(u * ISZ + i0 + il) * BB + b0 + bq * 8;
            *(v8s*)(xth + o) = hv;             // 64B segments, 4 lanes each
            *(v8s*)(xtl + o) = lv;
        }
    }
}

// ---------------- sgemm: s_part[b][ic][jd] for 2 j x 16 i per block ----------------
// R10-measured: 3.2us warm / ~7us cold; MfmaUtil 29% warm -- latency-bound,
// no internal lever. grid (72,5): blocks sharing an A-slice are 72 apart ->
// same XCD -> L2-shared (R6). c_ij precomputed in c_tab by mgemm's last block.
__global__ __launch_bounds__(256, 2) void sgemm_fused(
        const ush* __restrict__ xsh, const ush* __restrict__ xsl,
        const float* __restrict__ W, const float* __restrict__ c_tab,
        float* __restrict__ s_part, int it) {
    int ic = blockIdx.x, jh = blockIdx.y;
    int j0 = jh * 2, i0 = ic * ICH;
    int t = threadIdx.x, lane = t & 63, wv = t >> 6;
    int col = lane & 15, q = lane >> 4;

    __shared__ __align__(16) ush bh_[2][16][136];   // B^T hi [jj][d][k_local]
    __shared__ __align__(16) ush bl_[2][16][136];   // B^T lo
    __shared__ float c_lds[2][ICH];

    if (t < 2 * ICH) {
        int cj = t >> 4, ci = t & 15;
        c_lds[cj][ci] = (it == 0) ? (1.0f / 1152.0f)
                                  : c_tab[(size_t)(j0 + cj) * ISZ + i0 + ci];
    }
    __syncthreads();

    // build B tiles: 512 slots = (jj, ii, d), 2 per thread
    for (int slot = t; slot < 512; slot += 256) {
        int jj = slot >> 8, rem = slot & 255, ii = rem >> 4, d = rem & 15;
        const float* wp = W + (size_t)(i0 + ii) * 1280 + (j0 + jj) * 128 + d * 8;
        float4 wa = *(const float4*)wp;
        float4 wb = *(const float4*)(wp + 4);
        float ci = c_lds[jj][ii];
        float vals[8] = { wa.x * ci, wa.y * ci, wa.z * ci, wa.w * ci,
                          wb.x * ci, wb.y * ci, wb.z * ci, wb.w * ci };
        v8s hv, lv;
#pragma unroll
        for (int u = 0; u < 8; ++u) {
            ush h = f2bf(vals[u]);
            hv[u] = (short)h;
            lv[u] = (short)f2bf(vals[u] - bf2f(h));
        }
        *(v8s*)&bh_[jj][d][ii * 8] = hv;
        *(v8s*)&bl_[jj][d][ii * 8] = lv;
    }
    __syncthreads();

    int m_base = wv * 64;
    f4v acc[4][2];
#pragma unroll
    for (int mm = 0; mm < 4; ++mm)
#pragma unroll
        for (int jj = 0; jj < 2; ++jj) acc[mm][jj] = (f4v){0.f, 0.f, 0.f, 0.f};

#pragma unroll
    for (int s = 0; s < 4; ++s) {           // 4 k-steps x 32 k = 128 k (16 i)
        v8s bh0 = *(const v8s*)&bh_[0][col][s * 32 + q * 8];
        v8s bl0 = *(const v8s*)&bl_[0][col][s * 32 + q * 8];
        v8s bh1 = *(const v8s*)&bh_[1][col][s * 32 + q * 8];
        v8s bl1 = *(const v8s*)&bl_[1][col][s * 32 + q * 8];
        size_t abase = (size_t)(i0 + s * 4 + q) * 2048;
#pragma unroll
        for (int mm = 0; mm < 4; ++mm) {
            size_t ao = abase + (size_t)(m_base + mm * 16 + col) * 8;
            v8s ah = *(const v8s*)(xsh + ao);
            v8s al = *(const v8s*)(xsl + ao);
            acc[mm][0] = __builtin_amdgcn_mfma_f32_16x16x32_bf16(ah, bh0, acc[mm][0], 0, 0, 0);
            acc[mm][0] = __builtin_amdgcn_mfma_f32_16x16x32_bf16(ah, bl0, acc[mm][0], 0, 0, 0);
            acc[mm][0] = __builtin_amdgcn_mfma_f32_16x16x32_bf16(al, bh0, acc[mm][0], 0, 0, 0);
            acc[mm][1] = __builtin_amdgcn_mfma_f32_16x16x32_bf16(ah, bh1, acc[mm][1], 0, 0, 0);
            acc[mm][1] = __builtin_amdgcn_mfma_f32_16x16x32_bf16(ah, bl1, acc[mm][1], 0, 0, 0);
            acc[mm][1] = __builtin_amdgcn_mfma_f32_16x16x32_bf16(al, bh1, acc[mm][1], 0, 0, 0);
        }
    }
    // C/D: col = n, row = q*4+r (= b within m-tile)  [R7-verified]
    // s_part[b][ic][jd] (transposed) -> reduce reads contiguous 46KB/block
#pragma unroll
    for (int mm = 0; mm < 4; ++mm)
#pragma unroll
        for (int jj = 0; jj < 2; ++jj)
#pragma unroll
            for (int r = 0; r < 4; ++r)
                s_part[((size_t)(m_base + mm * 16 + q * 4 + r) * NIC + ic) * JD
                       + (j0 + jj) * DD + col] = acc[mm][jj][r];
}

// ---------------- reduce split-K + squash; v_out (last it) / vT bf16 (it<2) ----
// R12: 72-part sum batched 24-deep (was unroll-8): 9 -> 3 sequential LLC
// latency groups per block (~2.2us -> ~0.75us chain).
__global__ void reduce_squash(const float* __restrict__ s_part, float* __restrict__ v,
                              ush* __restrict__ vth, ush* __restrict__ vtl, int it) {
    int b = blockIdx.x, t = threadIdx.x;   // 192, t<160 active
    __shared__ float sm[JD];
    if (t < JD) {
        const float* sp = s_part + (size_t)b * NIC * JD + t;   // contiguous 46KB region
        float s = 0.f;
        float tmp[24];
#pragma unroll
        for (int c = 0; c < 3; ++c) {          // 72 parts = 3 batches x 24 in flight
#pragma unroll
            for (int u = 0; u < 24; ++u) tmp[u] = sp[(size_t)(c * 24 + u) * JD];
#pragma unroll
            for (int u = 0; u < 24; ++u) s += tmp[u];
        }
        sm[t] = s;
    }
    __syncthreads();
    if (t < JD) {
        int d = t & 15;
        float msq = 0.f;
#pragma unroll
        for (int j = 0; j < JJ; ++j) { float xx = sm[j * DD + d]; msq += xx * xx; }
        float val = msq / (1.f + msq) * sm[t] * rsqrtf(msq);
        if (it == 2) {
            v[(size_t)b * JD + t] = val;      // final output only
        } else {
            ush h = f2bf(val);
            vth[(size_t)t * BB + b] = h;
            vtl[(size_t)t * BB + b] = f2bf(val - bf2f(h));
        }
    }
}

// ---------------- mgemm + agreement epilogue [R7-verified] ----------------
// wave w -> mt = w/288, jobs (mt, 2*(w%288)+{0,1}): same-mt A reuse (R6).
// Last finished block computes c_tab = softmax(b_ij) for next sgemm (R6).
__global__ __launch_bounds__(256) void mgemm_agree(
        const ush* __restrict__ Ah, const ush* __restrict__ Al,
        const ush* __restrict__ Bh, const ush* __restrict__ Bl,
        const float* __restrict__ W, float* __restrict__ b_ij,
        float* __restrict__ c_tab, unsigned* __restrict__ done, int it) {
    int wv = threadIdx.x >> 6, lane = threadIdx.x & 63;
    int col = lane & 15, q = lane >> 4;
    int w = blockIdx.x * 4 + wv;        // 720 blocks -> waves 0..2879
    int mt = w / 288, nt2 = w % 288;
    int m0 = mt * 16;
#pragma unroll
    for (int rep = 0; rep < 2; ++rep) {
        int nt = nt2 * 2 + rep;
        int n0 = nt * 16;
        size_t aoff = (size_t)(m0 + col) * BB + q * 8;   // same both reps -> L1 hit
        size_t boff = (size_t)(n0 + col) * BB + q * 8;
        f4v acc = {0.f, 0.f, 0.f, 0.f};
#pragma unroll
        for (int s = 0; s < BB / 32; ++s) {
            v8s ah = *(const v8s*)(Ah + aoff);
            v8s al = *(const v8s*)(Al + aoff);
            v8s bh = *(const v8s*)(Bh + boff);
            v8s bl = *(const v8s*)(Bl + boff);
            acc = __builtin_amdgcn_mfma_f32_16x16x32_bf16(ah, bh, acc, 0, 0, 0);
            acc = __builtin_amdgcn_mfma_f32_16x16x32_bf16(ah, bl, acc, 0, 0, 0);
            acc = __builtin_amdgcn_mfma_f32_16x16x32_bf16(al, bh, acc, 0, 0, 0);
            aoff += 32; boff += 32;
        }
        int u = nt / 72;
        int i = (nt % 72) * 16 + col;
        const float* Wp = W + (size_t)i * 1280 + mt * 128 + q * 32 + u;
        float p = Wp[0] * acc[0] + Wp[8] * acc[1] + Wp[16] * acc[2] + Wp[24] * acc[3];
        p += __shfl_xor(p, 16, 64);
        p += __shfl_xor(p, 32, 64);
        if (q == 0) atomicAdd(&b_ij[(size_t)mt * ISZ + i], p * (1.0f / 256.0f));
    }

    // ---- last-block softmax precompute: c_tab[j][i] = softmax_i(b_ij[j][i]) ----
    __shared__ unsigned lastf;
    asm volatile("s_waitcnt vmcnt(0)" ::: "memory");   // our atomics complete at LLC
    __syncthreads();
    if (threadIdx.x == 0) {
        unsigned old = __hip_atomic_fetch_add(&done[it], 1u,
                           __ATOMIC_RELAXED, __HIP_MEMORY_SCOPE_AGENT);
        lastf = (old == 719u);
    }
    __syncthreads();
    if (lastf) {
        for (int j = wv; j < JJ; j += 4) {            // wave wv: j = wv, wv+4, wv+8
            const float* bp = b_ij + (size_t)j * ISZ;
            float vals[18];
#pragma unroll
            for (int k = 0; k < 18; ++k) vals[k] = bp[lane + 64 * k];
            float m = -1e30f;
#pragma unroll
            for (int k = 0; k < 18; ++k) m = fmaxf(m, vals[k]);
#pragma unroll
            for (int off = 32; off; off >>= 1) m = fmaxf(m, __shfl_xor(m, off, 64));
            float ssum = 0.f;
#pragma unroll
            for (int k = 0; k < 18; ++k) ssum += __expf(vals[k] - m);
#pragma unroll
            for (int off = 32; off; off >>= 1) ssum += __shfl_xor(ssum, off, 64);
            float inv = 1.f / ssum;
#pragma unroll
            for (int k = 0; k < 18; ++k)
                c_tab[(size_t)j * ISZ + lane + 64 * k] = __expf(vals[k] - m) * inv;
        }
    }
}

extern "C" void kernel_launch(void* const* d_in, const int* in_sizes, int n_in,
                              void* d_out, int out_size, void* d_ws, size_t ws_size,
                              hipStream_t stream) {
    const float* x = (const float*)d_in[0];   // (256, 8, 1152)
    const float* W = (const float*)d_in[1];   // (1, 1152, 10, 16, 8)
    float* v_out = (float*)d_out;             // (256, 10, 16, 1)

    float* b_ij  = (float*)d_ws;                           // 11,520 f
    float* c_tab = b_ij + ISZ * JJ;                        // 11,520 f
    float* dptr  = c_tab + ISZ * JJ;
    unsigned* done = (unsigned*)dptr;                      // 64 u32 (16 used)
    float* s_part = dptr + 64;                             // 256*72*160 f (transposed)
    ush* xsh = (ush*)(s_part + (size_t)BB * NIC * JD);     // [1152][2048]
    ush* xsl = xsh + (size_t)ISZ * 2048;
    ush* xth = xsl + (size_t)ISZ * 2048;                   // [9216][256]
    ush* xtl = xth + (size_t)K1 * BB;
    ush* vth = xtl + (size_t)K1 * BB;                      // [160][256]
    ush* vtl = vth + (size_t)JD * BB;

    hipLaunchKernelGGL(prep_kernel, dim3(18, 8), dim3(256), 0, stream,
                       x, xsh, xsl, xth, xtl, b_ij, done);
    for (int it = 0; it < 3; ++it) {
        hipLaunchKernelGGL(sgemm_fused, dim3(NIC, NJH), dim3(256), 0, stream,
                           xsh, xsl, W, c_tab, s_part, it);
        hipLaunchKernelGGL(reduce_squash, dim3(BB), dim3(192), 0, stream,
                           s_part, v_out, vth, vtl, it);
        if (it < 2) {
            hipLaunchKernelGGL(mgemm_agree, dim3(720), dim3(256), 0, stream,
                               vth, vtl, xth, xtl, W, b_ij, c_tab, done, it);
        }
    }
}